// Round 4
// baseline (218.286 us; speedup 1.0000x reference)
//
#include <hip/hip_runtime.h>
#include <math.h>

// Problem constants (x: [32, 256, 56, 56] fp32)
#define B_    32
#define C_    256
#define H_    56
#define W_    56
#define HW_   (H_ * W_)        // 3136
#define BHW_  (B_ * HW_)       // 100352
#define HW4_  (HW_ / 4)        // 784 float4 per (b,c) plane
#define NF4_  (BHW_ / 4)       // 25088 global float4 positions
#define GRID_ 512              // 2 blocks/CU exactly -> zero scheduling tail
#define F4PB_ (NF4_ / GRID_)   // 49 float4 per block (exact)
#define POSPB_ (BHW_ / GRID_)  // 196 float positions per block (exact)

typedef float f4v __attribute__((ext_vector_type(4)));

// ---------------------------------------------------------------------------
// Kernel 1: channel-wise mean + max -> pool [B, 2, HW].
// 512 blocks x 256 threads; block owns 49 consecutive float4 positions
// (perfectly equal work -> no CU scheduling tail; 3136 = 2^6*7^2 makes
// power-of-2 chunking impossible, so we eat a 49/64 lane-mask residue
// instead — wasted issue slots, zero wasted bandwidth).
// Thread layout: lane = t&31 (f4 position), cgrp = t>>5 (8 groups x 32 ch).
// ---------------------------------------------------------------------------
__global__ __launch_bounds__(256) void sa_reduce_kernel(
    const float* __restrict__ x, float* __restrict__ pool) {
  const int t = threadIdx.x;
  const int lane = t & 31;
  const int cgrp = t >> 5;
  const f4v* __restrict__ x4 = (const f4v*)x;
  f4v* __restrict__ p4 = (f4v*)pool;

  __shared__ f4v ssum[8][32];
  __shared__ f4v smax[8][32];

#pragma unroll
  for (int sub = 0; sub < 2; ++sub) {
    const int lidx = sub * 32 + lane;           // 0..48 valid
    const bool active = (lidx < F4PB_);
    const unsigned if4 = (unsigned)blockIdx.x * F4PB_ + (active ? lidx : 0);
    const unsigned bimg = if4 / HW4_;           // magic-mul
    const unsigned hw4 = if4 % HW4_;
    const unsigned base = (bimg * C_ + cgrp) * HW4_ + hw4;

    f4v s = {0.f, 0.f, 0.f, 0.f};
    f4v m = {-INFINITY, -INFINITY, -INFINITY, -INFINITY};
#pragma unroll 8
    for (int k = 0; k < 32; ++k) {              // c = cgrp + 8k
      f4v v = x4[base + (unsigned)(k * 8) * HW4_];
      s += v;
      m = (f4v){fmaxf(m.x, v.x), fmaxf(m.y, v.y),
                fmaxf(m.z, v.z), fmaxf(m.w, v.w)};
    }
    ssum[cgrp][lane] = s;
    smax[cgrp][lane] = m;
    __syncthreads();
    if (t < 32 && sub * 32 + t < F4PB_) {
      f4v S = ssum[0][t];
      f4v M = smax[0][t];
#pragma unroll
      for (int g = 1; g < 8; ++g) {
        f4v sg = ssum[g][t];
        f4v mg = smax[g][t];
        S += sg;
        M = (f4v){fmaxf(M.x, mg.x), fmaxf(M.y, mg.y),
                  fmaxf(M.z, mg.z), fmaxf(M.w, mg.w)};
      }
      const unsigned jf4 = (unsigned)blockIdx.x * F4PB_ + sub * 32 + t;
      const unsigned bb = jf4 / HW4_;
      const unsigned hh = jf4 % HW4_;
      p4[bb * 2 * HW4_ + hh]        = S * (1.0f / (float)C_);  // avg plane
      p4[bb * 2 * HW4_ + HW4_ + hh] = M;                       // max plane
    }
    __syncthreads();
  }
}

// ---------------------------------------------------------------------------
// Kernel 2: fused 7x7 SAME conv (2->1) + sigmoid (LDS gate) + broadcast apply.
// 512 blocks x 256 threads; block owns 196 consecutive gate positions
// (= 49 float4), perfectly equal work.
// Phase A: threads 0..195 each compute the full 98-tap conv for one position
//   from pool (L2/L3-resident) -> sigmoid -> sgate LDS. Gate never hits HBM.
// Phase B: lane = t&31, cgrp = t>>5; apply gate to 32 channels each with
//   coalesced float4 loads (x is L3-hot from K1) and nontemporal stores.
// ---------------------------------------------------------------------------
__global__ __launch_bounds__(256) void sa_conv_apply_kernel(
    const float* __restrict__ x, const float* __restrict__ pool,
    const float* __restrict__ wt, float* __restrict__ out) {
  const int t = threadIdx.x;
  __shared__ f4v sgate4[F4PB_];  // 196 gate floats

  // ---- Phase A: conv + sigmoid into LDS ----
  if (t < POSPB_) {
    const unsigned p = (unsigned)blockIdx.x * POSPB_ + (unsigned)t;
    const unsigned bimg = p / HW_;
    const unsigned hw = p % HW_;
    const int h = (int)(hw / W_);
    const int w = (int)(hw % W_);
    const float* pl0 = pool + (long)bimg * 2 * HW_;
    float acc = 0.f;
#pragma unroll
    for (int ic = 0; ic < 2; ++ic) {
      const float* pl = pl0 + ic * HW_;
      const float* wr0 = wt + ic * 49;
#pragma unroll
      for (int kh = 0; kh < 7; ++kh) {
        const int ih = h + kh - 3;
        if (ih < 0 || ih >= H_) continue;
        const float* row = pl + ih * W_;
        const float* wr = wr0 + kh * 7;
#pragma unroll
        for (int kw = 0; kw < 7; ++kw) {
          const int iw = w + kw - 3;
          if (iw < 0 || iw >= W_) continue;
          acc = fmaf(row[iw], wr[kw], acc);
        }
      }
    }
    ((float*)sgate4)[t] = 1.0f / (1.0f + __expf(-acc));
  }
  __syncthreads();

  // ---- Phase B: out = x * gate over 256 channels ----
  const int lane = t & 31;
  const int cgrp = t >> 5;
  const f4v* __restrict__ x4 = (const f4v*)x;
  f4v* __restrict__ o4 = (f4v*)out;
#pragma unroll
  for (int sub = 0; sub < 2; ++sub) {
    const int lidx = sub * 32 + lane;           // 0..48 valid
    if (lidx >= F4PB_) continue;
    const unsigned if4 = (unsigned)blockIdx.x * F4PB_ + lidx;
    const unsigned bimg = if4 / HW4_;
    const unsigned hw4 = if4 % HW4_;
    const unsigned base = (bimg * C_ + cgrp) * HW4_ + hw4;
    const f4v g = sgate4[lidx];
#pragma unroll 8
    for (int k = 0; k < 32; ++k) {              // c = cgrp + 8k
      const unsigned idx = base + (unsigned)(k * 8) * HW4_;
      f4v v = x4[idx];
      __builtin_nontemporal_store(v * g, &o4[idx]);
    }
  }
}

extern "C" void kernel_launch(void* const* d_in, const int* in_sizes, int n_in,
                              void* d_out, int out_size, void* d_ws, size_t ws_size,
                              hipStream_t stream) {
  const float* x  = (const float*)d_in[0];   // [32,256,56,56]
  const float* wc = (const float*)d_in[1];   // [1,2,7,7]
  float* out = (float*)d_out;
  float* pool = (float*)d_ws;                // [B,2,HW] = 802,816 B

  sa_reduce_kernel<<<GRID_, 256, 0, stream>>>(x, pool);
  sa_conv_apply_kernel<<<GRID_, 256, 0, stream>>>(x, pool, wc, out);
}

// Round 5
// 204.727 us; speedup vs baseline: 1.0662x; 1.0662x over previous
//
#include <hip/hip_runtime.h>
#include <math.h>

// Problem constants (x: [32, 256, 56, 56] fp32)
#define B_    32
#define C_    256
#define H_    56
#define W_    56
#define HW_   (H_ * W_)        // 3136
#define BHW_  (B_ * HW_)       // 100352
#define HW4_  (HW_ / 4)        // 784 float4 per (b,c) plane
#define NF4_  (BHW_ / 4)       // 25088 global float4 positions
#define GRID_ 1568             // chunk = 16 f4; 784 = 16*49 -> never straddles an image
#define CHUNKF4_ (NF4_ / GRID_)  // 16 float4 per block (exact)
#define POSPB_  (BHW_ / GRID_)   // 64 float positions per block (exact)

typedef float f4v __attribute__((ext_vector_type(4)));

// ---------------------------------------------------------------------------
// Kernel 1: channel-wise mean + max -> pool [B, 2, HW].
// 1568 blocks x 256 threads (24.5 waves/CU requested — R3(12.2 w/CU, 206us)
// vs R4(8 w/CU, 218us) says more resident waves = more outstanding loads for
// this HBM-streaming reduce). Block owns 16 consecutive float4 positions.
// lane = t&15 (f4 position), cgrp = t>>4 (16 groups x 16 channels).
// Wave load = 4 x 256 B contiguous segments per instruction — coalesced.
// ---------------------------------------------------------------------------
__global__ __launch_bounds__(256) void sa_reduce_kernel(
    const float* __restrict__ x, float* __restrict__ pool) {
  const int t = threadIdx.x;
  const int lane = t & 15;
  const int cgrp = t >> 4;
  const unsigned if4 = (unsigned)blockIdx.x * CHUNKF4_ + lane;  // < 25088
  const unsigned bimg = if4 / HW4_;          // magic-mul
  const unsigned hw4 = if4 % HW4_;
  const f4v* __restrict__ x4 = (const f4v*)x;
  const unsigned base = (bimg * C_ + cgrp) * HW4_ + hw4;

  f4v s = {0.f, 0.f, 0.f, 0.f};
  f4v m = {-INFINITY, -INFINITY, -INFINITY, -INFINITY};
#pragma unroll 8
  for (int k = 0; k < 16; ++k) {             // c = cgrp + 16k
    f4v v = x4[base + (unsigned)(k * 16) * HW4_];
    s += v;
    m = (f4v){fmaxf(m.x, v.x), fmaxf(m.y, v.y),
              fmaxf(m.z, v.z), fmaxf(m.w, v.w)};
  }

  __shared__ f4v ssum[16][16];
  __shared__ f4v smax[16][16];
  ssum[cgrp][lane] = s;
  smax[cgrp][lane] = m;
  __syncthreads();

  if (t < 16) {
    f4v S = ssum[0][t];
    f4v M = smax[0][t];
#pragma unroll
    for (int g = 1; g < 16; ++g) {
      f4v sg = ssum[g][t];
      f4v mg = smax[g][t];
      S += sg;
      M = (f4v){fmaxf(M.x, mg.x), fmaxf(M.y, mg.y),
                fmaxf(M.z, mg.z), fmaxf(M.w, mg.w)};
    }
    f4v* p4 = (f4v*)pool;
    const unsigned jf4 = (unsigned)blockIdx.x * CHUNKF4_ + t;
    const unsigned bb = jf4 / HW4_;
    const unsigned hh = jf4 % HW4_;
    p4[bb * 2 * HW4_ + hh]        = S * (1.0f / (float)C_);  // avg plane
    p4[bb * 2 * HW4_ + HW4_ + hh] = M;                       // max plane
  }
}

// ---------------------------------------------------------------------------
// Kernel 2: fused 7x7 SAME conv (2->1) + sigmoid (LDS gate) + broadcast apply.
// 1568 blocks x 256 threads; block owns 64 consecutive gate positions.
// Phase A: threads 0..127 = 64 positions x 2 input channels; 49-tap partials
//   from pool (L2/L3-resident) pair-summed via LDS -> sigmoid -> sgate LDS.
//   Gate never touches HBM.
// Phase B: lane = t&15, cgrp = t>>4; each thread applies the gate to 16
//   channels with coalesced float4 loads (x L3-warm from K1) + NT stores.
// ---------------------------------------------------------------------------
__global__ __launch_bounds__(256) void sa_conv_apply_kernel(
    const float* __restrict__ x, const float* __restrict__ pool,
    const float* __restrict__ wt, float* __restrict__ out) {
  const int t = threadIdx.x;
  __shared__ float partial[128];
  __shared__ f4v sgate4[CHUNKF4_];  // 64 gate floats

  // ---- Phase A: conv + sigmoid into LDS ----
  if (t < 2 * POSPB_) {
    const int pos = t >> 1;        // 0..63
    const int ic = t & 1;
    const unsigned p = (unsigned)blockIdx.x * POSPB_ + (unsigned)pos;
    const unsigned bimg = p / HW_;
    const unsigned hw = p % HW_;
    const int h = (int)(hw / W_);
    const int w = (int)(hw % W_);
    const float* pl = pool + ((long)bimg * 2 + ic) * HW_;
    const float* wr0 = wt + ic * 49;
    float acc = 0.f;
#pragma unroll
    for (int kh = 0; kh < 7; ++kh) {
      const int ih = h + kh - 3;
      if (ih < 0 || ih >= H_) continue;
      const float* row = pl + ih * W_;
      const float* wr = wr0 + kh * 7;
#pragma unroll
      for (int kw = 0; kw < 7; ++kw) {
        const int iw = w + kw - 3;
        if (iw < 0 || iw >= W_) continue;
        acc = fmaf(row[iw], wr[kw], acc);
      }
    }
    partial[t] = acc;
  }
  __syncthreads();
  if (t < POSPB_) {
    float a = partial[2 * t] + partial[2 * t + 1];
    ((float*)sgate4)[t] = 1.0f / (1.0f + __expf(-a));
  }
  __syncthreads();

  // ---- Phase B: out = x * gate over 256 channels ----
  const int lane = t & 15;
  const int cgrp = t >> 4;
  const unsigned if4 = (unsigned)blockIdx.x * CHUNKF4_ + lane;
  const unsigned bimg = if4 / HW4_;
  const unsigned hw4 = if4 % HW4_;
  const unsigned base = (bimg * C_ + cgrp) * HW4_ + hw4;
  const f4v* __restrict__ x4 = (const f4v*)x;
  f4v* __restrict__ o4 = (f4v*)out;
  const f4v g = sgate4[lane];
#pragma unroll 8
  for (int k = 0; k < 16; ++k) {             // c = cgrp + 16k
    const unsigned idx = base + (unsigned)(k * 16) * HW4_;
    f4v v = x4[idx];
    __builtin_nontemporal_store(v * g, &o4[idx]);
  }
}

extern "C" void kernel_launch(void* const* d_in, const int* in_sizes, int n_in,
                              void* d_out, int out_size, void* d_ws, size_t ws_size,
                              hipStream_t stream) {
  const float* x  = (const float*)d_in[0];   // [32,256,56,56]
  const float* wc = (const float*)d_in[1];   // [1,2,7,7]
  float* out = (float*)d_out;
  float* pool = (float*)d_ws;                // [B,2,HW] = 802,816 B

  sa_reduce_kernel<<<GRID_, 256, 0, stream>>>(x, pool);
  sa_conv_apply_kernel<<<GRID_, 256, 0, stream>>>(x, pool, wc, out);
}